// Round 10
// baseline (175.293 us; speedup 1.0000x reference)
//
#include <hip/hip_runtime.h>
#include <hip/hip_bf16.h>
#include <math.h>

#define BT     1024   // B*T
#define NH     8
#define SEGLEN 32
#define NSEG   16     // segments per sequence (T=512)
#define NBH    16     // B*H
#define QKS    136    // Qt/Kt LDS row stride (shorts)
#define VTS    40     // VT/KhT LDS row stride
#define AMS    40     // Am LDS row stride

typedef __attribute__((ext_vector_type(8))) short short8;
typedef __attribute__((ext_vector_type(4))) short sh4;
typedef __attribute__((ext_vector_type(4))) float f32x4;

__device__ __forceinline__ float bitf(short u) {
    union { float f; unsigned i; } x; x.i = ((unsigned)(unsigned short)u) << 16; return x.f;
}
__device__ __forceinline__ short f2bf(float f) {   // RNE f32->bf16
    union { float f; unsigned u; } x; x.f = f;
    unsigned r = x.u + 0x7FFF + ((x.u >> 16) & 1);
    return (short)(r >> 16);
}
// async global->LDS, 16B per lane; LDS dest = wave-uniform base + lane*16
__device__ __forceinline__ void gload_lds16(const short* g, short* l) {
    __builtin_amdgcn_global_load_lds(
        (const __attribute__((address_space(1))) unsigned int*)g,
        (__attribute__((address_space(3))) unsigned int*)l, 16, 0, 0);
}

// ---------------- fused pre-cast: W^T (z=0..4) and X (z=5) -> bf16 ----------------
__global__ __launch_bounds__(256) void cast_all(
    const float* __restrict__ Wq, const float* __restrict__ Wk,
    const float* __restrict__ Wv, const float* __restrict__ Wg,
    const float* __restrict__ Wo, const float* __restrict__ X,
    short* __restrict__ WT, short* __restrict__ Xb)
{
    const int z = blockIdx.z;
    const int tid = threadIdx.x;
    if (z == 5) {                           // cast X
        const int id = blockIdx.y * 32 + blockIdx.x;
        const int i = id * 1024 + tid * 4;
        float4 a = *(const float4*)(X + i);
        sh4 v;
        v[0] = f2bf(a.x); v[1] = f2bf(a.y); v[2] = f2bf(a.z); v[3] = f2bf(a.w);
        *(sh4*)(Xb + i) = v;
        return;
    }
    const float* W = (z == 0) ? Wq : (z == 1) ? Wk : (z == 2) ? Wv : (z == 3) ? Wg : Wo;
    short* T = WT + (size_t)z * (1u << 20);
    __shared__ float tile[32][33];
    const int k0 = blockIdx.y * 32, n0 = blockIdx.x * 32;
    const int row = tid >> 3, c4 = (tid & 7) << 2;
    float4 f = *(const float4*)(W + (size_t)(k0 + row) * 1024 + n0 + c4);
    tile[row][c4 + 0] = f.x; tile[row][c4 + 1] = f.y;
    tile[row][c4 + 2] = f.z; tile[row][c4 + 3] = f.w;
    __syncthreads();
    short* o = T + (size_t)(n0 + row) * 1024 + k0 + c4;
    o[0] = f2bf(tile[c4 + 0][row]); o[1] = f2bf(tile[c4 + 1][row]);
    o[2] = f2bf(tile[c4 + 2][row]); o[3] = f2bf(tile[c4 + 3][row]);
}

// ---------------- MFMA GEMM: Xb(bf16)@W -> bf16 out; 64x64 tiles, 4 blocks/CU ----------------
__global__ __launch_bounds__(256) void proj_gemm(
    const short* __restrict__ Xb, const short* __restrict__ WT,
    short* __restrict__ QKVG)
{
    const int z = blockIdx.z;
    const float scale = (z == 0) ? 0.08838834764831845f : 1.0f;  // HK^-0.5 on q
    short* C = QKVG + (size_t)z * (1u << 20);
    const short* B = WT + (size_t)z * (1u << 20);

    __shared__ __align__(16) short As[8 * 64 * 8];    // 8 KB
    __shared__ __align__(16) short Bs[8 * 64 * 8];    // 8 KB
    const int tid = threadIdx.x;
    const int wave = tid >> 6, lane = tid & 63;
    const int wm = (wave >> 1) * 32, wn = (wave & 1) * 32;
    const int m15 = lane & 15, q = lane >> 4;
    const int m0 = blockIdx.y * 64, n0 = blockIdx.x * 64;

    f32x4 acc[2][2];
    #pragma unroll
    for (int i = 0; i < 2; i++)
        #pragma unroll
        for (int j = 0; j < 2; j++)
            acc[i][j] = (f32x4){0.f, 0.f, 0.f, 0.f};

    for (int kb0 = 0; kb0 < 1024; kb0 += 64) {
        __syncthreads();
        #pragma unroll
        for (int c = 0; c < 2; c++) {
            const int k8 = wave * 2 + c;
            gload_lds16(Xb + (size_t)(m0 + lane) * 1024 + kb0 + k8 * 8, &As[(k8 * 64) * 8]);
            gload_lds16(B  + (size_t)(n0 + lane) * 1024 + kb0 + k8 * 8, &Bs[(k8 * 64) * 8]);
        }
        __syncthreads();
        #pragma unroll
        for (int s = 0; s < 2; s++) {
            const int k8 = s * 4 + q;
            short8 af[2], bf[2];
            #pragma unroll
            for (int i = 0; i < 2; i++)
                af[i] = *(const short8*)&As[(k8 * 64 + wm + i * 16 + m15) * 8];
            #pragma unroll
            for (int j = 0; j < 2; j++)
                bf[j] = *(const short8*)&Bs[(k8 * 64 + wn + j * 16 + m15) * 8];
            #pragma unroll
            for (int i = 0; i < 2; i++)
                #pragma unroll
                for (int j = 0; j < 2; j++)
                    acc[i][j] = __builtin_amdgcn_mfma_f32_16x16x32_bf16(af[i], bf[j], acc[i][j], 0, 0, 0);
        }
    }
    #pragma unroll
    for (int i = 0; i < 2; i++)
        #pragma unroll
        for (int j = 0; j < 2; j++)
            #pragma unroll
            for (int rr = 0; rr < 4; rr++)
                C[(size_t)(m0 + wm + i * 16 + q * 4 + rr) * 1024 + n0 + wn + j * 16 + m15] =
                    f2bf(acc[i][j][rr] * scale);
}

// ---------------- MFMA GEMM: Obf(bf16)@WoT -> out f32; tile 64x64 ----------------
__global__ __launch_bounds__(256) void wo_gemm(
    const short* __restrict__ A, const short* __restrict__ B, float* __restrict__ C)
{
    __shared__ __align__(16) short As[8 * 64 * 8];
    __shared__ __align__(16) short Bs[8 * 64 * 8];
    const int tid = threadIdx.x;
    const int wave = tid >> 6, lane = tid & 63;
    const int wm = (wave >> 1) * 32, wn = (wave & 1) * 32;
    const int m15 = lane & 15, q = lane >> 4;
    const int m0 = blockIdx.y * 64, n0 = blockIdx.x * 64;

    f32x4 acc[2][2];
    #pragma unroll
    for (int i = 0; i < 2; i++)
        #pragma unroll
        for (int j = 0; j < 2; j++)
            acc[i][j] = (f32x4){0.f, 0.f, 0.f, 0.f};

    for (int kb0 = 0; kb0 < 1024; kb0 += 64) {
        __syncthreads();
        #pragma unroll
        for (int c = 0; c < 2; c++) {
            const int k8 = wave * 2 + c;
            gload_lds16(A + (size_t)(m0 + lane) * 1024 + kb0 + k8 * 8, &As[(k8 * 64) * 8]);
            gload_lds16(B + (size_t)(n0 + lane) * 1024 + kb0 + k8 * 8, &Bs[(k8 * 64) * 8]);
        }
        __syncthreads();
        #pragma unroll
        for (int s = 0; s < 2; s++) {
            const int k8 = s * 4 + q;
            short8 af[2], bf[2];
            #pragma unroll
            for (int i = 0; i < 2; i++)
                af[i] = *(const short8*)&As[(k8 * 64 + wm + i * 16 + m15) * 8];
            #pragma unroll
            for (int j = 0; j < 2; j++)
                bf[j] = *(const short8*)&Bs[(k8 * 64 + wn + j * 16 + m15) * 8];
            #pragma unroll
            for (int i = 0; i < 2; i++)
                #pragma unroll
                for (int j = 0; j < 2; j++)
                    acc[i][j] = __builtin_amdgcn_mfma_f32_16x16x32_bf16(af[i], bf[j], acc[i][j], 0, 0, 0);
        }
    }
    #pragma unroll
    for (int i = 0; i < 2; i++)
        #pragma unroll
        for (int j = 0; j < 2; j++)
            #pragma unroll
            for (int rr = 0; rr < 4; rr++)
                C[(size_t)(m0 + wm + i * 16 + q * 4 + rr) * 1024 + n0 + wn + j * 16 + m15] =
                    acc[i][j][rr];
}

// ---------------- low-rank gate (bf16 X): gk = logsigmoid(x@Wgk1@Wgk2 + b)/16 ----------------
__global__ __launch_bounds__(256) void gk_proj(
    const short* __restrict__ Xb, const float* __restrict__ Wgk1,
    const float* __restrict__ Wgk2, const float* __restrict__ bgk2,
    short* __restrict__ GK)
{
    const int row = blockIdx.x, tid = threadIdx.x;
    float p[16];
    #pragma unroll
    for (int j = 0; j < 16; j++) p[j] = 0.f;
    for (int d = tid; d < 1024; d += 256) {
        float xv = bitf(Xb[(size_t)row * 1024 + d]);
        #pragma unroll
        for (int j = 0; j < 16; j++)
            p[j] = fmaf(xv, Wgk1[d * 16 + j], p[j]);
    }
    #pragma unroll
    for (int j = 0; j < 16; j++)
        for (int off = 32; off; off >>= 1) p[j] += __shfl_down(p[j], off);
    __shared__ float zp[4][16];
    __shared__ float z[16];
    const int lane = tid & 63, w = tid >> 6;
    if (lane == 0) {
        #pragma unroll
        for (int j = 0; j < 16; j++) zp[w][j] = p[j];
    }
    __syncthreads();
    if (tid < 16) z[tid] = zp[0][tid] + zp[1][tid] + zp[2][tid] + zp[3][tid];
    __syncthreads();
    for (int c = tid; c < 1024; c += 256) {
        float acc = bgk2[c];
        #pragma unroll
        for (int j = 0; j < 16; j++)
            acc = fmaf(z[j], Wgk2[j * 1024 + c], acc);
        float ls = fminf(acc, 0.f) - log1pf(expf(-fabsf(acc)));  // logsigmoid
        GK[(size_t)row * 1024 + c] = f2bf(ls * (1.f / 16.f));
    }
}

// ---------------- phase A: chunked scan via MFMA ----------------
// S_local stored TRANSPOSED: SS[vch][kch] (B-operand layout for corr MFMA).
__global__ __launch_bounds__(256) void scan_chunk(
    const short* __restrict__ Q, const short* __restrict__ K,
    const short* __restrict__ V, short* GKQT,
    float* __restrict__ O, short* __restrict__ SS, float* __restrict__ DSEG)
{
    const int seg = blockIdx.x;   // 0..15
    const int bh  = blockIdx.y;   // 0..15
    const int b = bh >> 3, h = bh & 7;
    const int tid = threadIdx.x;
    const size_t rowbase = (size_t)(b * 512 + seg * SEGLEN) * 1024 + h * 128;

    __shared__ __align__(16) short Qt[32 * QKS];
    __shared__ __align__(16) short Kt[32 * QKS];
    __shared__ __align__(16) short Vs[32 * 128];
    __shared__ __align__(16) short VT[128 * VTS];
    __shared__ __align__(16) short KhT[128 * VTS];
    __shared__ __align__(16) short Am[32 * AMS];

    if (tid < 128) {
        const int ch = tid;
        float gsum = 0.f;
        float ktf[32];
        #pragma unroll
        for (int t = 0; t < 32; t++) {
            const size_t a = rowbase + (size_t)t * 1024 + ch;
            float g  = bitf(GKQT[a]);
            float kv = bitf(K[a]);
            float qv = bitf(Q[a]);
            gsum += g;
            float eg  = expf(gsum);
            float emg = expf(-gsum);
            short qts = f2bf(qv * eg);
            Qt[t * QKS + ch] = qts;
            GKQT[a] = qts;                       // write Q~ over GK
            float ktv = kv * emg;
            Kt[t * QKS + ch] = f2bf(ktv);
            ktf[t] = ktv;
        }
        float eGend = expf(gsum);
        DSEG[(bh * NSEG + seg) * 128 + ch] = eGend;
        #pragma unroll
        for (int t4 = 0; t4 < 8; t4++) {
            sh4 p;
            p[0] = f2bf(ktf[4 * t4 + 0] * eGend);
            p[1] = f2bf(ktf[4 * t4 + 1] * eGend);
            p[2] = f2bf(ktf[4 * t4 + 2] * eGend);
            p[3] = f2bf(ktf[4 * t4 + 3] * eGend);
            *(sh4*)&KhT[ch * VTS + 4 * t4] = p;
        }
    } else {
        const int u = tid - 128;
        #pragma unroll
        for (int i = 0; i < 4; i++) {
            const int idx = u + i * 128;          // short8 index, 512 total
            const int t = idx >> 4, c = idx & 15;
            short8 vv = *(const short8*)&V[rowbase + (size_t)t * 1024 + c * 8];
            *(short8*)&Vs[t * 128 + c * 8] = vv;
        }
    }
    __syncthreads();
    {
        const int ch = tid >> 1, t0 = (tid & 1) * 16;
        #pragma unroll
        for (int j = 0; j < 4; j++) {
            sh4 p;
            p[0] = Vs[(t0 + 4 * j + 0) * 128 + ch];
            p[1] = Vs[(t0 + 4 * j + 1) * 128 + ch];
            p[2] = Vs[(t0 + 4 * j + 2) * 128 + ch];
            p[3] = Vs[(t0 + 4 * j + 3) * 128 + ch];
            *(sh4*)&VT[ch * VTS + t0 + 4 * j] = p;
        }
    }
    __syncthreads();

    const int wave = tid >> 6, lane = tid & 63;
    const int m15 = lane & 15, q = lane >> 4;

    // GEMM1: A = Qt(32x128) @ Kt^T, causal mask, -> Am bf16
    {
        const int mi = wave >> 1, ni = wave & 1;
        f32x4 a1 = (f32x4){0.f, 0.f, 0.f, 0.f};
        #pragma unroll
        for (int kc = 0; kc < 4; kc++) {
            short8 af = *(const short8*)&Qt[(mi * 16 + m15) * QKS + kc * 32 + q * 8];
            short8 bf = *(const short8*)&Kt[(ni * 16 + m15) * QKS + kc * 32 + q * 8];
            a1 = __builtin_amdgcn_mfma_f32_16x16x32_bf16(af, bf, a1, 0, 0, 0);
        }
        #pragma unroll
        for (int rr = 0; rr < 4; rr++) {
            const int t = mi * 16 + q * 4 + rr, s = ni * 16 + m15;
            Am[t * AMS + s] = (t >= s) ? f2bf(a1[rr]) : (short)0;
        }
    }
    __syncthreads();

    // GEMM2: O_intra = Am(32x32) @ V(32x128) -> O global (f32)
    {
        const int mi = wave >> 1, nb = (wave & 1) * 4;
        short8 af = *(const short8*)&Am[(mi * 16 + m15) * AMS + q * 8];
        #pragma unroll
        for (int jj = 0; jj < 4; jj++) {
            short8 bf = *(const short8*)&VT[((nb + jj) * 16 + m15) * VTS + q * 8];
            f32x4 a2 = (f32x4){0.f, 0.f, 0.f, 0.f};
            a2 = __builtin_amdgcn_mfma_f32_16x16x32_bf16(af, bf, a2, 0, 0, 0);
            #pragma unroll
            for (int rr = 0; rr < 4; rr++)
                O[rowbase + (size_t)(mi * 16 + q * 4 + rr) * 1024 + (nb + jj) * 16 + m15] = a2[rr];
        }
    }

    // GEMM3: S^T[vch][kch] = V^T @ Kh -> SS bf16 (A/B swapped vs old orientation)
    {
        const size_t sbase = (size_t)(bh * NSEG + seg) * 16384;
        #pragma unroll
        for (int m2 = 0; m2 < 2; m2++) {
            const int mrow = wave * 2 + m2;      // vch tile
            short8 af = *(const short8*)&VT[(mrow * 16 + m15) * VTS + q * 8];
            #pragma unroll
            for (int ni = 0; ni < 8; ni++) {     // kch tile
                short8 bf = *(const short8*)&KhT[(ni * 16 + m15) * VTS + q * 8];
                f32x4 a3 = (f32x4){0.f, 0.f, 0.f, 0.f};
                a3 = __builtin_amdgcn_mfma_f32_16x16x32_bf16(af, bf, a3, 0, 0, 0);
                #pragma unroll
                for (int rr = 0; rr < 4; rr++)
                    SS[sbase + (size_t)(mrow * 16 + q * 4 + rr) * 128 + ni * 16 + m15] =
                        f2bf(a3[rr]);
            }
        }
    }
}

// ---------------- phase B: stitch segment states (SS layout [vch][kch]) ----------------
__global__ __launch_bounds__(256) void stitch(
    short* __restrict__ SS, const float* __restrict__ DSEG)
{
    const int slice = blockIdx.x;   // 0..7: vch rows [slice*16, slice*16+16)
    const int bh = blockIdx.y, tid = threadIdx.x;
    __shared__ float dloc[NSEG][128];
    for (int i = tid; i < NSEG * 128; i += 256)
        dloc[i >> 7][i & 127] = DSEG[(bh * NSEG + (i >> 7)) * 128 + (i & 127)];
    __syncthreads();
    const int kch = tid & 127;      // e & 127 == tid & 127 for all j
    float run[8];
    #pragma unroll
    for (int j = 0; j < 8; j++) run[j] = 0.f;
    for (int seg = 0; seg < NSEG; seg++) {
        const size_t base = (size_t)(bh * NSEG + seg) * 16384 + slice * 2048;
        const float dk = dloc[seg][kch];
        #pragma unroll
        for (int j = 0; j < 8; j++) {
            const int e = j * 256 + tid;
            float tmp = bitf(SS[base + e]);
            SS[base + e] = f2bf(run[j]);               // S_in for this segment
            run[j] = fmaf(run[j], dk, tmp);
        }
    }
}

// ---------------- phase C: MFMA correction + fused gated RMSNorm -> bf16 ----------------
// o = O_intra + Q~(32x128) @ S_in^T(128x128); rowwise RMS; swish gate; store bf16.
__global__ __launch_bounds__(256) void corr_gnorm(
    const short* __restrict__ QT, const short* __restrict__ SS,
    const float* __restrict__ O, const short* __restrict__ G,
    const float* __restrict__ gnw, short* __restrict__ Obf)
{
    const int seg = blockIdx.x;      // 0..15 (seg 0's S_in is zeros from stitch)
    const int bh = blockIdx.y;
    const int b = bh >> 3, h = bh & 7;
    const int tid = threadIdx.x;
    const int wave = tid >> 6, lane = tid & 63;
    const int m15 = lane & 15, q = lane >> 4;
    const size_t rowbase = (size_t)(b * 512 + seg * SEGLEN) * 1024 + h * 128;
    const size_t sbase = (size_t)(bh * NSEG + seg) * 16384;

    __shared__ __align__(16) short Qs[16 * 32 * 8];    // [k8][t][8]    8 KB
    __shared__ __align__(16) short Ss[16 * 128 * 8];   // [k8][vch][8] 32 KB
    __shared__ float red[4][16];

    // DMA stage Q~ (32 t x 128 kch): flat = k8*32 + t
    #pragma unroll
    for (int c = 0; c < 2; c++) {
        const int fb = wave * 128 + c * 64;
        const int flat = fb + lane;
        const int k8 = flat >> 5, t = flat & 31;
        gload_lds16(QT + rowbase + (size_t)t * 1024 + k8 * 8, &Qs[fb * 8]);
    }
    // DMA stage S^T (128 vch x 128 kch): flat = k8*128 + vch
    #pragma unroll
    for (int c = 0; c < 8; c++) {
        const int fb = wave * 512 + c * 64;
        const int flat = fb + lane;
        const int k8 = flat >> 7, vch = flat & 127;
        gload_lds16(SS + sbase + (size_t)vch * 128 + k8 * 8, &Ss[fb * 8]);
    }
    __syncthreads();

    const int mt = wave >> 1, nh2 = wave & 1;
    f32x4 acc[4];
    #pragma unroll
    for (int nt = 0; nt < 4; nt++) acc[nt] = (f32x4){0.f, 0.f, 0.f, 0.f};
    #pragma unroll
    for (int kb = 0; kb < 4; kb++) {
        short8 af = *(const short8*)&Qs[((kb * 4 + q) * 32 + mt * 16 + m15) * 8];
        #pragma unroll
        for (int nt = 0; nt < 4; nt++) {
            short8 bf = *(const short8*)&Ss[((kb * 4 + q) * 128 + nh2 * 64 + nt * 16 + m15) * 8];
            acc[nt] = __builtin_amdgcn_mfma_f32_16x16x32_bf16(af, bf, acc[nt], 0, 0, 0);
        }
    }

    // o = O_intra + corr; partial row sums of o^2
    float o[4][4];
    float ssq[4] = {0.f, 0.f, 0.f, 0.f};
    #pragma unroll
    for (int nt = 0; nt < 4; nt++) {
        const int vch = nh2 * 64 + nt * 16 + m15;
        #pragma unroll
        for (int rr = 0; rr < 4; rr++) {
            const int t = mt * 16 + q * 4 + rr;
            float ov = O[rowbase + (size_t)t * 1024 + vch] + acc[nt][rr];
            o[nt][rr] = ov;
            ssq[rr] = fmaf(ov, ov, ssq[rr]);
        }
    }
    #pragma unroll
    for (int rr = 0; rr < 4; rr++) {
        ssq[rr] += __shfl_xor(ssq[rr], 1);
        ssq[rr] += __shfl_xor(ssq[rr], 2);
        ssq[rr] += __shfl_xor(ssq[rr], 4);
        ssq[rr] += __shfl_xor(ssq[rr], 8);
    }
    if (m15 == 0) {
        #pragma unroll
        for (int rr = 0; rr < 4; rr++) red[wave][q * 4 + rr] = ssq[rr];
    }
    __syncthreads();
    float rsq[4];
    #pragma unroll
    for (int rr = 0; rr < 4; rr++) {
        float ms = (red[wave][q * 4 + rr] + red[wave ^ 1][q * 4 + rr]) * (1.f / 128.f);
        rsq[rr] = rsqrtf(ms + 1e-5f);
    }
    #pragma unroll
    for (int nt = 0; nt < 4; nt++) {
        const int vch = nh2 * 64 + nt * 16 + m15;
        const float gw = gnw[vch];
        #pragma unroll
        for (int rr = 0; rr < 4; rr++) {
            const int t = mt * 16 + q * 4 + rr;
            float g = bitf(G[rowbase + (size_t)t * 1024 + vch]);
            float sg = g / (1.f + expf(-g));
            Obf[rowbase + (size_t)t * 1024 + vch] = f2bf(o[nt][rr] * rsq[rr] * gw * sg);
        }
    }
}

extern "C" void kernel_launch(void* const* d_in, const int* in_sizes, int n_in,
                              void* d_out, int out_size, void* d_ws, size_t ws_size,
                              hipStream_t stream)
{
    const float* X    = (const float*)d_in[0];
    const float* Wq   = (const float*)d_in[1];
    const float* Wk   = (const float*)d_in[2];
    const float* Wv   = (const float*)d_in[3];
    const float* Wg   = (const float*)d_in[4];
    const float* Wgk1 = (const float*)d_in[5];
    const float* Wgk2 = (const float*)d_in[6];
    const float* bgk2 = (const float*)d_in[7];
    const float* gnw  = (const float*)d_in[8];
    const float* Wo   = (const float*)d_in[9];
    float* OUT = (float*)d_out;   // reference output is float32

    // workspace layout (~34.1 MiB):
    short* QKVG = (short*)d_ws;               // 4 x 1M bf16 (Q,K,V,G)     [8 MiB]
    short* GK   = QKVG + (4u << 20);          // 1M bf16: GK -> Q~         [2 MiB]
    float* Ob   = (float*)(GK + (1u << 20));  // 1M f32                    [4 MiB]
    short* SS   = (short*)(Ob + (1u << 20));  // 16bh x 16seg x [vch][kch] bf16 [8 MiB]
    float* DS   = (float*)(SS + (4u << 20));  // 32K f32                   [128 KiB]
    short* WT   = (short*)(DS + 32768);       // 5 x 1M bf16 (W^T)         [10 MiB]
    short* Xb   = WT + (5u << 20);            // 1M bf16 (X cast)          [2 MiB]
    short* Obf  = QKVG;                       // alias Q (dead after scan_chunk)

    cast_all<<<dim3(32, 32, 6), 256, 0, stream>>>(Wq, Wk, Wv, Wg, Wo, X, WT, Xb);
    proj_gemm<<<dim3(16, 16, 4), 256, 0, stream>>>(Xb, WT, QKVG);
    gk_proj<<<dim3(BT), 256, 0, stream>>>(Xb, Wgk1, Wgk2, bgk2, GK);
    scan_chunk<<<dim3(NSEG, NBH), 256, 0, stream>>>(
        QKVG, QKVG + (1u << 20), QKVG + (2u << 20), GK, Ob, SS, DS);
    stitch<<<dim3(8, NBH), 256, 0, stream>>>(SS, DS);
    corr_gnorm<<<dim3(NSEG, NBH), 256, 0, stream>>>(
        GK, SS, Ob, QKVG + (3u << 20), gnw, Obf);
    wo_gemm<<<dim3(16, 16), 256, 0, stream>>>(Obf, WT + (4u << 20), OUT);
}

// Round 11
// 174.088 us; speedup vs baseline: 1.0069x; 1.0069x over previous
//
#include <hip/hip_runtime.h>
#include <hip/hip_bf16.h>
#include <math.h>

#define BT     1024   // B*T
#define NH     8
#define SEGLEN 32
#define NSEG   16     // segments per sequence (T=512)
#define NBH    16     // B*H
#define QKS    136    // Qt/Kt LDS row stride (shorts)
#define VTS    40     // VT/KhT LDS row stride
#define AMS    40     // Am LDS row stride

typedef __attribute__((ext_vector_type(8))) short short8;
typedef __attribute__((ext_vector_type(4))) short sh4;
typedef __attribute__((ext_vector_type(4))) float f32x4;

__device__ __forceinline__ float bitf(short u) {
    union { float f; unsigned i; } x; x.i = ((unsigned)(unsigned short)u) << 16; return x.f;
}
__device__ __forceinline__ short f2bf(float f) {   // RNE f32->bf16
    union { float f; unsigned u; } x; x.f = f;
    unsigned r = x.u + 0x7FFF + ((x.u >> 16) & 1);
    return (short)(r >> 16);
}
// async global->LDS, 16B per lane; LDS dest = wave-uniform base + lane*16
__device__ __forceinline__ void gload_lds16(const short* g, short* l) {
    __builtin_amdgcn_global_load_lds(
        (const __attribute__((address_space(1))) unsigned int*)g,
        (__attribute__((address_space(3))) unsigned int*)l, 16, 0, 0);
}

// ---------------- fused pre-cast: W^T (z=0..4) and X (z=5) -> bf16 ----------------
__global__ __launch_bounds__(256) void cast_all(
    const float* __restrict__ Wq, const float* __restrict__ Wk,
    const float* __restrict__ Wv, const float* __restrict__ Wg,
    const float* __restrict__ Wo, const float* __restrict__ X,
    short* __restrict__ WT, short* __restrict__ Xb)
{
    const int z = blockIdx.z;
    const int tid = threadIdx.x;
    if (z == 5) {                           // cast X
        const int id = blockIdx.y * 32 + blockIdx.x;
        const int i = id * 1024 + tid * 4;
        float4 a = *(const float4*)(X + i);
        sh4 v;
        v[0] = f2bf(a.x); v[1] = f2bf(a.y); v[2] = f2bf(a.z); v[3] = f2bf(a.w);
        *(sh4*)(Xb + i) = v;
        return;
    }
    const float* W = (z == 0) ? Wq : (z == 1) ? Wk : (z == 2) ? Wv : (z == 3) ? Wg : Wo;
    short* T = WT + (size_t)z * (1u << 20);
    __shared__ float tile[32][33];
    const int k0 = blockIdx.y * 32, n0 = blockIdx.x * 32;
    const int row = tid >> 3, c4 = (tid & 7) << 2;
    float4 f = *(const float4*)(W + (size_t)(k0 + row) * 1024 + n0 + c4);
    tile[row][c4 + 0] = f.x; tile[row][c4 + 1] = f.y;
    tile[row][c4 + 2] = f.z; tile[row][c4 + 3] = f.w;
    __syncthreads();
    short* o = T + (size_t)(n0 + row) * 1024 + k0 + c4;
    o[0] = f2bf(tile[c4 + 0][row]); o[1] = f2bf(tile[c4 + 1][row]);
    o[2] = f2bf(tile[c4 + 2][row]); o[3] = f2bf(tile[c4 + 3][row]);
}

// ---------------- MFMA GEMM Xb@W (z=0..3) -> bf16; z=4: low-rank gate (1 wave/row) ----------------
__global__ __launch_bounds__(256) void proj_gk(
    const short* __restrict__ Xb, const short* __restrict__ WT,
    short* __restrict__ QKVG,
    const float* __restrict__ Wgk1, const float* __restrict__ Wgk2,
    const float* __restrict__ bgk2, short* __restrict__ GK)
{
    const int z = blockIdx.z;
    const int tid = threadIdx.x;
    const int wave = tid >> 6, lane = tid & 63;

    if (z == 4) {   // gate: gk = logsigmoid(x@Wgk1@Wgk2 + b)/16, one wave per row
        const int row = (blockIdx.y * 16 + blockIdx.x) * 4 + wave;
        float p[16];
        #pragma unroll
        for (int j = 0; j < 16; j++) p[j] = 0.f;
        for (int d8 = 0; d8 < 16; d8++) {
            const int d = d8 * 64 + lane;
            float xv = bitf(Xb[(size_t)row * 1024 + d]);
            #pragma unroll
            for (int j = 0; j < 16; j++)
                p[j] = fmaf(xv, Wgk1[d * 16 + j], p[j]);
        }
        #pragma unroll
        for (int j = 0; j < 16; j++)
            #pragma unroll
            for (int off = 32; off; off >>= 1)
                p[j] += __shfl_xor(p[j], off);
        for (int c8 = 0; c8 < 16; c8++) {
            const int c = c8 * 64 + lane;
            float acc = bgk2[c];
            #pragma unroll
            for (int j = 0; j < 16; j++)
                acc = fmaf(p[j], Wgk2[j * 1024 + c], acc);
            float ls = fminf(acc, 0.f) - log1pf(expf(-fabsf(acc)));
            GK[(size_t)row * 1024 + c] = f2bf(ls * (1.f / 16.f));
        }
        return;
    }

    const float scale = (z == 0) ? 0.08838834764831845f : 1.0f;  // HK^-0.5 on q
    short* C = QKVG + (size_t)z * (1u << 20);
    const short* B = WT + (size_t)z * (1u << 20);

    __shared__ __align__(16) short As[8 * 64 * 8];    // 8 KB
    __shared__ __align__(16) short Bs[8 * 64 * 8];    // 8 KB
    const int wm = (wave >> 1) * 32, wn = (wave & 1) * 32;
    const int m15 = lane & 15, q = lane >> 4;
    const int m0 = blockIdx.y * 64, n0 = blockIdx.x * 64;

    f32x4 acc[2][2];
    #pragma unroll
    for (int i = 0; i < 2; i++)
        #pragma unroll
        for (int j = 0; j < 2; j++)
            acc[i][j] = (f32x4){0.f, 0.f, 0.f, 0.f};

    for (int kb0 = 0; kb0 < 1024; kb0 += 64) {
        __syncthreads();
        #pragma unroll
        for (int c = 0; c < 2; c++) {
            const int k8 = wave * 2 + c;
            gload_lds16(Xb + (size_t)(m0 + lane) * 1024 + kb0 + k8 * 8, &As[(k8 * 64) * 8]);
            gload_lds16(B  + (size_t)(n0 + lane) * 1024 + kb0 + k8 * 8, &Bs[(k8 * 64) * 8]);
        }
        __syncthreads();
        #pragma unroll
        for (int s = 0; s < 2; s++) {
            const int k8 = s * 4 + q;
            short8 af[2], bf[2];
            #pragma unroll
            for (int i = 0; i < 2; i++)
                af[i] = *(const short8*)&As[(k8 * 64 + wm + i * 16 + m15) * 8];
            #pragma unroll
            for (int j = 0; j < 2; j++)
                bf[j] = *(const short8*)&Bs[(k8 * 64 + wn + j * 16 + m15) * 8];
            #pragma unroll
            for (int i = 0; i < 2; i++)
                #pragma unroll
                for (int j = 0; j < 2; j++)
                    acc[i][j] = __builtin_amdgcn_mfma_f32_16x16x32_bf16(af[i], bf[j], acc[i][j], 0, 0, 0);
        }
    }
    #pragma unroll
    for (int i = 0; i < 2; i++)
        #pragma unroll
        for (int j = 0; j < 2; j++)
            #pragma unroll
            for (int rr = 0; rr < 4; rr++)
                C[(size_t)(m0 + wm + i * 16 + q * 4 + rr) * 1024 + n0 + wn + j * 16 + m15] =
                    f2bf(acc[i][j][rr] * scale);
}

// ---------------- MFMA GEMM: Obf(bf16)@WoT -> out f32; tile 64x64 ----------------
__global__ __launch_bounds__(256) void wo_gemm(
    const short* __restrict__ A, const short* __restrict__ B, float* __restrict__ C)
{
    __shared__ __align__(16) short As[8 * 64 * 8];
    __shared__ __align__(16) short Bs[8 * 64 * 8];
    const int tid = threadIdx.x;
    const int wave = tid >> 6, lane = tid & 63;
    const int wm = (wave >> 1) * 32, wn = (wave & 1) * 32;
    const int m15 = lane & 15, q = lane >> 4;
    const int m0 = blockIdx.y * 64, n0 = blockIdx.x * 64;

    f32x4 acc[2][2];
    #pragma unroll
    for (int i = 0; i < 2; i++)
        #pragma unroll
        for (int j = 0; j < 2; j++)
            acc[i][j] = (f32x4){0.f, 0.f, 0.f, 0.f};

    for (int kb0 = 0; kb0 < 1024; kb0 += 64) {
        __syncthreads();
        #pragma unroll
        for (int c = 0; c < 2; c++) {
            const int k8 = wave * 2 + c;
            gload_lds16(A + (size_t)(m0 + lane) * 1024 + kb0 + k8 * 8, &As[(k8 * 64) * 8]);
            gload_lds16(B + (size_t)(n0 + lane) * 1024 + kb0 + k8 * 8, &Bs[(k8 * 64) * 8]);
        }
        __syncthreads();
        #pragma unroll
        for (int s = 0; s < 2; s++) {
            const int k8 = s * 4 + q;
            short8 af[2], bf[2];
            #pragma unroll
            for (int i = 0; i < 2; i++)
                af[i] = *(const short8*)&As[(k8 * 64 + wm + i * 16 + m15) * 8];
            #pragma unroll
            for (int j = 0; j < 2; j++)
                bf[j] = *(const short8*)&Bs[(k8 * 64 + wn + j * 16 + m15) * 8];
            #pragma unroll
            for (int i = 0; i < 2; i++)
                #pragma unroll
                for (int j = 0; j < 2; j++)
                    acc[i][j] = __builtin_amdgcn_mfma_f32_16x16x32_bf16(af[i], bf[j], acc[i][j], 0, 0, 0);
        }
    }
    #pragma unroll
    for (int i = 0; i < 2; i++)
        #pragma unroll
        for (int j = 0; j < 2; j++)
            #pragma unroll
            for (int rr = 0; rr < 4; rr++)
                C[(size_t)(m0 + wm + i * 16 + q * 4 + rr) * 1024 + n0 + wn + j * 16 + m15] =
                    acc[i][j][rr];
}

// ---------------- phase A: chunked scan via MFMA ----------------
// Prologue parallelized over both t-halves; V staged by DMA; O_intra stored bf16.
// S_local stored TRANSPOSED: SS[vch][kch].
__global__ __launch_bounds__(256) void scan_chunk(
    const short* __restrict__ Q, const short* __restrict__ K,
    const short* __restrict__ V, short* GKQT,
    short* __restrict__ O, short* __restrict__ SS, float* __restrict__ DSEG)
{
    const int seg = blockIdx.x;   // 0..15
    const int bh  = blockIdx.y;   // 0..15
    const int b = bh >> 3, h = bh & 7;
    const int tid = threadIdx.x;
    const int wave = tid >> 6, lane = tid & 63;
    const size_t rowbase = (size_t)(b * 512 + seg * SEGLEN) * 1024 + h * 128;

    __shared__ __align__(16) short Qt[32 * QKS];
    __shared__ __align__(16) short Kt[32 * QKS];
    __shared__ __align__(16) short Vs[32 * 128];
    __shared__ __align__(16) short VT[128 * VTS];
    __shared__ __align__(16) short KhT[128 * VTS];
    __shared__ __align__(16) short Am[32 * AMS];
    __shared__ float htot[2][128];

    // DMA stage V: flat f = t*16 + c8 (512 chunks of 8 shorts)
    #pragma unroll
    for (int c = 0; c < 2; c++) {
        const int fb = (wave * 2 + c) * 64;
        const int f = fb + lane;
        const int t = f >> 4, c8 = f & 15;
        gload_lds16(V + rowbase + (size_t)t * 1024 + c8 * 8, &Vs[fb * 8]);
    }

    // prologue: ch = tid&127, th2 = tid>>7 handles 16 t's
    const int ch = tid & 127, th2 = tid >> 7;
    float g[16], kv[16], qv[16];
    #pragma unroll
    for (int tt = 0; tt < 16; tt++) {
        const size_t a = rowbase + (size_t)(th2 * 16 + tt) * 1024 + ch;
        g[tt] = bitf(GKQT[a]); kv[tt] = bitf(K[a]); qv[tt] = bitf(Q[a]);
    }
    float run = 0.f;
    #pragma unroll
    for (int tt = 0; tt < 16; tt++) { run += g[tt]; g[tt] = run; }   // local prefix
    htot[th2][ch] = run;
    __syncthreads();                                  // htot ready
    const float base_ = th2 ? htot[0][ch] : 0.f;
    const float eGend = expf(htot[0][ch] + htot[1][ch]);
    if (th2 == 0) DSEG[(bh * NSEG + seg) * 128 + ch] = eGend;
    #pragma unroll
    for (int tt = 0; tt < 16; tt++) {
        const int t = th2 * 16 + tt;
        const size_t a = rowbase + (size_t)t * 1024 + ch;
        const float Gc = base_ + g[tt];
        const float eg = expf(Gc);
        short qts = f2bf(qv[tt] * eg);
        Qt[t * QKS + ch] = qts;
        GKQT[a] = qts;                       // write Q~ over GK
        float ktv = kv[tt] * expf(-Gc);
        Kt[t * QKS + ch] = f2bf(ktv);
        KhT[ch * VTS + t] = f2bf(ktv * eGend);
    }
    __syncthreads();                                  // Qt/Kt/KhT + V DMA drained
    // V transpose: VT[ch][t]
    {
        const int vch = tid >> 1, t0 = (tid & 1) * 16;
        #pragma unroll
        for (int j = 0; j < 4; j++) {
            sh4 p;
            p[0] = Vs[(t0 + 4 * j + 0) * 128 + vch];
            p[1] = Vs[(t0 + 4 * j + 1) * 128 + vch];
            p[2] = Vs[(t0 + 4 * j + 2) * 128 + vch];
            p[3] = Vs[(t0 + 4 * j + 3) * 128 + vch];
            *(sh4*)&VT[vch * VTS + t0 + 4 * j] = p;
        }
    }
    __syncthreads();

    const int m15 = lane & 15, q = lane >> 4;

    // GEMM1: A = Qt(32x128) @ Kt^T, causal mask, -> Am bf16
    {
        const int mi = wave >> 1, ni = wave & 1;
        f32x4 a1 = (f32x4){0.f, 0.f, 0.f, 0.f};
        #pragma unroll
        for (int kc = 0; kc < 4; kc++) {
            short8 af = *(const short8*)&Qt[(mi * 16 + m15) * QKS + kc * 32 + q * 8];
            short8 bf = *(const short8*)&Kt[(ni * 16 + m15) * QKS + kc * 32 + q * 8];
            a1 = __builtin_amdgcn_mfma_f32_16x16x32_bf16(af, bf, a1, 0, 0, 0);
        }
        #pragma unroll
        for (int rr = 0; rr < 4; rr++) {
            const int t = mi * 16 + q * 4 + rr, s = ni * 16 + m15;
            Am[t * AMS + s] = (t >= s) ? f2bf(a1[rr]) : (short)0;
        }
    }
    __syncthreads();

    // GEMM2: O_intra = Am(32x32) @ V(32x128) -> O global (bf16)
    {
        const int mi = wave >> 1, nb = (wave & 1) * 4;
        short8 af = *(const short8*)&Am[(mi * 16 + m15) * AMS + q * 8];
        #pragma unroll
        for (int jj = 0; jj < 4; jj++) {
            short8 bf = *(const short8*)&VT[((nb + jj) * 16 + m15) * VTS + q * 8];
            f32x4 a2 = (f32x4){0.f, 0.f, 0.f, 0.f};
            a2 = __builtin_amdgcn_mfma_f32_16x16x32_bf16(af, bf, a2, 0, 0, 0);
            #pragma unroll
            for (int rr = 0; rr < 4; rr++)
                O[rowbase + (size_t)(mi * 16 + q * 4 + rr) * 1024 + (nb + jj) * 16 + m15] =
                    f2bf(a2[rr]);
        }
    }

    // GEMM3: S^T[vch][kch] = V^T @ Kh -> SS bf16
    {
        const size_t sbase = (size_t)(bh * NSEG + seg) * 16384;
        #pragma unroll
        for (int m2 = 0; m2 < 2; m2++) {
            const int mrow = wave * 2 + m2;      // vch tile
            short8 af = *(const short8*)&VT[(mrow * 16 + m15) * VTS + q * 8];
            #pragma unroll
            for (int ni = 0; ni < 8; ni++) {     // kch tile
                short8 bf = *(const short8*)&KhT[(ni * 16 + m15) * VTS + q * 8];
                f32x4 a3 = (f32x4){0.f, 0.f, 0.f, 0.f};
                a3 = __builtin_amdgcn_mfma_f32_16x16x32_bf16(af, bf, a3, 0, 0, 0);
                #pragma unroll
                for (int rr = 0; rr < 4; rr++)
                    SS[sbase + (size_t)(mrow * 16 + q * 4 + rr) * 128 + ni * 16 + m15] =
                        f2bf(a3[rr]);
            }
        }
    }
}

// ---------------- phase B: stitch segment states (SS layout [vch][kch], packed dwords) ----------------
__global__ __launch_bounds__(256) void stitch(
    short* __restrict__ SS, const float* __restrict__ DSEG)
{
    const int slice = blockIdx.x;   // 0..15: vch rows [slice*8, slice*8+8)
    const int bh = blockIdx.y, tid = threadIdx.x;
    __shared__ float dloc[NSEG][128];
    for (int i = tid; i < NSEG * 128; i += 256)
        dloc[i >> 7][i & 127] = DSEG[(bh * NSEG + (i >> 7)) * 128 + (i & 127)];
    __syncthreads();
    const int kch0 = (tid * 2) & 127;
    float run[2][2] = {{0.f, 0.f}, {0.f, 0.f}};
    for (int seg = 0; seg < NSEG; seg++) {
        const size_t base = (size_t)(bh * NSEG + seg) * 16384 + slice * 1024;
        const float d0 = dloc[seg][kch0], d1 = dloc[seg][kch0 + 1];
        #pragma unroll
        for (int j = 0; j < 2; j++) {
            unsigned* p = (unsigned*)&SS[base + j * 512 + tid * 2];
            unsigned u = *p;
            float t0 = bitf((short)(u & 0xFFFF));
            float t1 = bitf((short)(u >> 16));
            unsigned w0 = (unsigned short)f2bf(run[j][0]);
            unsigned w1 = (unsigned short)f2bf(run[j][1]);
            *p = w0 | (w1 << 16);                      // S_in for this segment
            run[j][0] = fmaf(run[j][0], d0, t0);
            run[j][1] = fmaf(run[j][1], d1, t1);
        }
    }
}

// ---------------- phase C: MFMA correction + fused gated RMSNorm -> bf16 ----------------
__global__ __launch_bounds__(256) void corr_gnorm(
    const short* __restrict__ QT, const short* __restrict__ SS,
    const short* __restrict__ O, const short* __restrict__ G,
    const float* __restrict__ gnw, short* __restrict__ Obf)
{
    const int seg = blockIdx.x;      // 0..15 (seg 0's S_in is zeros from stitch)
    const int bh = blockIdx.y;
    const int b = bh >> 3, h = bh & 7;
    const int tid = threadIdx.x;
    const int wave = tid >> 6, lane = tid & 63;
    const int m15 = lane & 15, q = lane >> 4;
    const size_t rowbase = (size_t)(b * 512 + seg * SEGLEN) * 1024 + h * 128;
    const size_t sbase = (size_t)(bh * NSEG + seg) * 16384;

    __shared__ __align__(16) short Qs[16 * 32 * 8];    // [k8][t][8]    8 KB
    __shared__ __align__(16) short Ss[16 * 128 * 8];   // [k8][vch][8] 32 KB
    __shared__ __align__(16) short Gs[16 * 32 * 8];    // [vch8][t][8]  8 KB
    __shared__ __align__(16) short Os[16 * 32 * 8];    // [vch8][t][8]  8 KB
    __shared__ float red[4][16];

    // DMA stage Q~ (32 t x 128 kch): flat = k8*32 + t
    #pragma unroll
    for (int c = 0; c < 2; c++) {
        const int fb = (wave * 2 + c) * 64;
        const int f = fb + lane;
        const int k8 = f >> 5, t = f & 31;
        gload_lds16(QT + rowbase + (size_t)t * 1024 + k8 * 8, &Qs[fb * 8]);
    }
    // DMA stage G and O (32 t x 128 vch): flat = vch8*32 + t
    #pragma unroll
    for (int c = 0; c < 2; c++) {
        const int fb = (wave * 2 + c) * 64;
        const int f = fb + lane;
        const int v8 = f >> 5, t = f & 31;
        gload_lds16(G + rowbase + (size_t)t * 1024 + v8 * 8, &Gs[fb * 8]);
        gload_lds16(O + rowbase + (size_t)t * 1024 + v8 * 8, &Os[fb * 8]);
    }
    // DMA stage S^T (128 vch x 128 kch): flat = k8*128 + vch
    #pragma unroll
    for (int c = 0; c < 8; c++) {
        const int fb = wave * 512 + c * 64;
        const int f = fb + lane;
        const int k8 = f >> 7, vch = f & 127;
        gload_lds16(SS + sbase + (size_t)vch * 128 + k8 * 8, &Ss[fb * 8]);
    }
    __syncthreads();

    const int mt = wave >> 1, nh2 = wave & 1;
    f32x4 acc[4];
    #pragma unroll
    for (int nt = 0; nt < 4; nt++) acc[nt] = (f32x4){0.f, 0.f, 0.f, 0.f};
    #pragma unroll
    for (int kb = 0; kb < 4; kb++) {
        short8 af = *(const short8*)&Qs[((kb * 4 + q) * 32 + mt * 16 + m15) * 8];
        #pragma unroll
        for (int nt = 0; nt < 4; nt++) {
            short8 bf = *(const short8*)&Ss[((kb * 4 + q) * 128 + nh2 * 64 + nt * 16 + m15) * 8];
            acc[nt] = __builtin_amdgcn_mfma_f32_16x16x32_bf16(af, bf, acc[nt], 0, 0, 0);
        }
    }

    // o = O_intra + corr; partial row sums of o^2
    float o[4][4];
    float ssq[4] = {0.f, 0.f, 0.f, 0.f};
    #pragma unroll
    for (int nt = 0; nt < 4; nt++) {
        const int vch = nh2 * 64 + nt * 16 + m15;
        #pragma unroll
        for (int rr = 0; rr < 4; rr++) {
            const int t = mt * 16 + q * 4 + rr;
            float ov = bitf(Os[((vch >> 3) * 32 + t) * 8 + (vch & 7)]) + acc[nt][rr];
            o[nt][rr] = ov;
            ssq[rr] = fmaf(ov, ov, ssq[rr]);
        }
    }
    #pragma unroll
    for (int rr = 0; rr < 4; rr++) {
        ssq[rr] += __shfl_xor(ssq[rr], 1);
        ssq[rr] += __shfl_xor(ssq[rr], 2);
        ssq[rr] += __shfl_xor(ssq[rr], 4);
        ssq[rr] += __shfl_xor(ssq[rr], 8);
    }
    if (m15 == 0) {
        #pragma unroll
        for (int rr = 0; rr < 4; rr++) red[wave][q * 4 + rr] = ssq[rr];
    }
    __syncthreads();
    float rsq[4];
    #pragma unroll
    for (int rr = 0; rr < 4; rr++) {
        float ms = (red[wave][q * 4 + rr] + red[wave ^ 1][q * 4 + rr]) * (1.f / 128.f);
        rsq[rr] = rsqrtf(ms + 1e-5f);
    }
    #pragma unroll
    for (int nt = 0; nt < 4; nt++) {
        const int vch = nh2 * 64 + nt * 16 + m15;
        const float gw = gnw[vch];
        #pragma unroll
        for (int rr = 0; rr < 4; rr++) {
            const int t = mt * 16 + q * 4 + rr;
            float g = bitf(Gs[((vch >> 3) * 32 + t) * 8 + (vch & 7)]);
            float sg = g / (1.f + expf(-g));
            Obf[rowbase + (size_t)t * 1024 + vch] = f2bf(o[nt][rr] * rsq[rr] * gw * sg);
        }
    }
}

extern "C" void kernel_launch(void* const* d_in, const int* in_sizes, int n_in,
                              void* d_out, int out_size, void* d_ws, size_t ws_size,
                              hipStream_t stream)
{
    const float* X    = (const float*)d_in[0];
    const float* Wq   = (const float*)d_in[1];
    const float* Wk   = (const float*)d_in[2];
    const float* Wv   = (const float*)d_in[3];
    const float* Wg   = (const float*)d_in[4];
    const float* Wgk1 = (const float*)d_in[5];
    const float* Wgk2 = (const float*)d_in[6];
    const float* bgk2 = (const float*)d_in[7];
    const float* gnw  = (const float*)d_in[8];
    const float* Wo   = (const float*)d_in[9];
    float* OUT = (float*)d_out;   // reference output is float32

    // workspace layout (shorts unless noted, ~32 MiB):
    short* QKVG = (short*)d_ws;               // 4 x 1M bf16 (Q,K,V,G)     [8 MiB]
    short* GK   = QKVG + (4u << 20);          // 1M bf16: GK -> Q~         [2 MiB]
    short* Ob   = GK + (1u << 20);            // 1M bf16 O_intra           [2 MiB]
    short* SS   = Ob + (1u << 20);            // 16bh x 16seg x [vch][kch] [8 MiB]
    float* DS   = (float*)(SS + (4u << 20));  // 32K f32                   [128 KiB]
    short* WT   = (short*)(DS + 32768);       // 5 x 1M bf16 (W^T)         [10 MiB]
    short* Xb   = WT + (5u << 20);            // 1M bf16 (X cast)          [2 MiB]
    short* Obf  = QKVG;                       // alias Q (dead after scan_chunk)

    cast_all<<<dim3(32, 32, 6), 256, 0, stream>>>(Wq, Wk, Wv, Wg, Wo, X, WT, Xb);
    proj_gk<<<dim3(16, 16, 5), 256, 0, stream>>>(Xb, WT, QKVG, Wgk1, Wgk2, bgk2, GK);
    scan_chunk<<<dim3(NSEG, NBH), 256, 0, stream>>>(
        QKVG, QKVG + (1u << 20), QKVG + (2u << 20), GK, Ob, SS, DS);
    stitch<<<dim3(16, NBH), 256, 0, stream>>>(SS, DS);
    corr_gnorm<<<dim3(NSEG, NBH), 256, 0, stream>>>(
        GK, SS, Ob, QKVG + (3u << 20), gnw, Obf);
    wo_gemm<<<dim3(16, 16), 256, 0, stream>>>(Obf, WT + (4u << 20), OUT);
}

// Round 12
// 158.323 us; speedup vs baseline: 1.1072x; 1.0996x over previous
//
#include <hip/hip_runtime.h>
#include <hip/hip_bf16.h>
#include <math.h>

#define BT     1024   // B*T
#define NH     8
#define SEGLEN 32
#define NSEG   16     // segments per sequence (T=512)
#define NBH    16     // B*H
#define QKS    136    // Qt/Kt LDS row stride (shorts)
#define VTS    40     // VT/KhT LDS row stride
#define AMS    40     // Am LDS row stride

typedef __attribute__((ext_vector_type(8))) short short8;
typedef __attribute__((ext_vector_type(4))) short sh4;
typedef __attribute__((ext_vector_type(4))) float f32x4;

__device__ __forceinline__ float bitf(short u) {
    union { float f; unsigned i; } x; x.i = ((unsigned)(unsigned short)u) << 16; return x.f;
}
__device__ __forceinline__ short f2bf(float f) {   // RNE f32->bf16
    union { float f; unsigned u; } x; x.f = f;
    unsigned r = x.u + 0x7FFF + ((x.u >> 16) & 1);
    return (short)(r >> 16);
}
// async global->LDS, 16B per lane; LDS dest = wave-uniform base + lane*16
__device__ __forceinline__ void gload_lds16(const short* g, short* l) {
    __builtin_amdgcn_global_load_lds(
        (const __attribute__((address_space(1))) unsigned int*)g,
        (__attribute__((address_space(3))) unsigned int*)l, 16, 0, 0);
}

// ---------------- fused pre-cast: W^T (z=0..4), X (z=5), Wgk1^T (z=6) -> bf16 ----------------
__global__ __launch_bounds__(256) void cast_all(
    const float* __restrict__ Wq, const float* __restrict__ Wk,
    const float* __restrict__ Wv, const float* __restrict__ Wg,
    const float* __restrict__ Wo, const float* __restrict__ X,
    const float* __restrict__ Wgk1,
    short* __restrict__ WT, short* __restrict__ Xb, short* __restrict__ Wgk1T)
{
    const int z = blockIdx.z;
    const int tid = threadIdx.x;
    if (z == 5) {                           // cast X
        const int id = blockIdx.y * 32 + blockIdx.x;
        const int i = id * 1024 + tid * 4;
        float4 a = *(const float4*)(X + i);
        sh4 v;
        v[0] = f2bf(a.x); v[1] = f2bf(a.y); v[2] = f2bf(a.z); v[3] = f2bf(a.w);
        *(sh4*)(Xb + i) = v;
        return;
    }
    if (z == 6) {                           // Wgk1 (1024x16) -> Wgk1T (16x1024) bf16
        const int id = blockIdx.y * 32 + blockIdx.x;
        if (id >= 16) return;
        const int d = id * 64 + (tid & 63), jj = tid >> 6;   // jj: 4 j's
        float4 w = *(const float4*)(Wgk1 + d * 16 + jj * 4);
        Wgk1T[(jj * 4 + 0) * 1024 + d] = f2bf(w.x);
        Wgk1T[(jj * 4 + 1) * 1024 + d] = f2bf(w.y);
        Wgk1T[(jj * 4 + 2) * 1024 + d] = f2bf(w.z);
        Wgk1T[(jj * 4 + 3) * 1024 + d] = f2bf(w.w);
        return;
    }
    const float* W = (z == 0) ? Wq : (z == 1) ? Wk : (z == 2) ? Wv : (z == 3) ? Wg : Wo;
    short* T = WT + (size_t)z * (1u << 20);
    __shared__ float tile[32][33];
    const int k0 = blockIdx.y * 32, n0 = blockIdx.x * 32;
    const int row = tid >> 3, c4 = (tid & 7) << 2;
    float4 f = *(const float4*)(W + (size_t)(k0 + row) * 1024 + n0 + c4);
    tile[row][c4 + 0] = f.x; tile[row][c4 + 1] = f.y;
    tile[row][c4 + 2] = f.z; tile[row][c4 + 3] = f.w;
    __syncthreads();
    short* o = T + (size_t)(n0 + row) * 1024 + k0 + c4;
    o[0] = f2bf(tile[c4 + 0][row]); o[1] = f2bf(tile[c4 + 1][row]);
    o[2] = f2bf(tile[c4 + 2][row]); o[3] = f2bf(tile[c4 + 3][row]);
}

// ---------------- MFMA GEMM: Xb(bf16)@W -> bf16; tile 64x128, grid (8,16,4) ----------------
__global__ __launch_bounds__(256) void proj_gemm(
    const short* __restrict__ Xb, const short* __restrict__ WT,
    short* __restrict__ QKVG)
{
    const int z = blockIdx.z;
    const float scale = (z == 0) ? 0.08838834764831845f : 1.0f;  // HK^-0.5 on q
    short* C = QKVG + (size_t)z * (1u << 20);
    const short* B = WT + (size_t)z * (1u << 20);

    __shared__ __align__(16) short As[8 * 64 * 8];    // 8 KB
    __shared__ __align__(16) short Bs[8 * 128 * 8];   // 16 KB
    const int tid = threadIdx.x;
    const int wave = tid >> 6, lane = tid & 63;
    const int wm = (wave >> 1) * 32, wn = (wave & 1) * 64;
    const int m15 = lane & 15, q = lane >> 4;
    const int m0 = blockIdx.y * 64, n0 = blockIdx.x * 128;

    f32x4 acc[2][4];
    #pragma unroll
    for (int i = 0; i < 2; i++)
        #pragma unroll
        for (int j = 0; j < 4; j++)
            acc[i][j] = (f32x4){0.f, 0.f, 0.f, 0.f};

    for (int kb0 = 0; kb0 < 1024; kb0 += 64) {
        __syncthreads();
        #pragma unroll
        for (int c = 0; c < 2; c++) {
            const int k8 = wave * 2 + c;
            gload_lds16(Xb + (size_t)(m0 + lane) * 1024 + kb0 + k8 * 8,
                        &As[(k8 * 64) * 8]);
            #pragma unroll
            for (int rh = 0; rh < 2; rh++)
                gload_lds16(B + (size_t)(n0 + rh * 64 + lane) * 1024 + kb0 + k8 * 8,
                            &Bs[(k8 * 128 + rh * 64) * 8]);
        }
        __syncthreads();
        #pragma unroll
        for (int s = 0; s < 2; s++) {
            const int k8 = s * 4 + q;
            short8 af[2], bf[4];
            #pragma unroll
            for (int i = 0; i < 2; i++)
                af[i] = *(const short8*)&As[(k8 * 64 + wm + i * 16 + m15) * 8];
            #pragma unroll
            for (int j = 0; j < 4; j++)
                bf[j] = *(const short8*)&Bs[(k8 * 128 + wn + j * 16 + m15) * 8];
            #pragma unroll
            for (int i = 0; i < 2; i++)
                #pragma unroll
                for (int j = 0; j < 4; j++)
                    acc[i][j] = __builtin_amdgcn_mfma_f32_16x16x32_bf16(af[i], bf[j], acc[i][j], 0, 0, 0);
        }
    }
    #pragma unroll
    for (int i = 0; i < 2; i++)
        #pragma unroll
        for (int j = 0; j < 4; j++)
            #pragma unroll
            for (int rr = 0; rr < 4; rr++)
                C[(size_t)(m0 + wm + i * 16 + q * 4 + rr) * 1024 + n0 + wn + j * 16 + m15] =
                    f2bf(acc[i][j][rr] * scale);
}

// ---------------- MFMA GEMM: Obf(bf16)@WoT -> out f32; tile 64x64 ----------------
__global__ __launch_bounds__(256) void wo_gemm(
    const short* __restrict__ A, const short* __restrict__ B, float* __restrict__ C)
{
    __shared__ __align__(16) short As[8 * 64 * 8];
    __shared__ __align__(16) short Bs[8 * 64 * 8];
    const int tid = threadIdx.x;
    const int wave = tid >> 6, lane = tid & 63;
    const int wm = (wave >> 1) * 32, wn = (wave & 1) * 32;
    const int m15 = lane & 15, q = lane >> 4;
    const int m0 = blockIdx.y * 64, n0 = blockIdx.x * 64;

    f32x4 acc[2][2];
    #pragma unroll
    for (int i = 0; i < 2; i++)
        #pragma unroll
        for (int j = 0; j < 2; j++)
            acc[i][j] = (f32x4){0.f, 0.f, 0.f, 0.f};

    for (int kb0 = 0; kb0 < 1024; kb0 += 64) {
        __syncthreads();
        #pragma unroll
        for (int c = 0; c < 2; c++) {
            const int k8 = wave * 2 + c;
            gload_lds16(A + (size_t)(m0 + lane) * 1024 + kb0 + k8 * 8, &As[(k8 * 64) * 8]);
            gload_lds16(B + (size_t)(n0 + lane) * 1024 + kb0 + k8 * 8, &Bs[(k8 * 64) * 8]);
        }
        __syncthreads();
        #pragma unroll
        for (int s = 0; s < 2; s++) {
            const int k8 = s * 4 + q;
            short8 af[2], bf[2];
            #pragma unroll
            for (int i = 0; i < 2; i++)
                af[i] = *(const short8*)&As[(k8 * 64 + wm + i * 16 + m15) * 8];
            #pragma unroll
            for (int j = 0; j < 2; j++)
                bf[j] = *(const short8*)&Bs[(k8 * 64 + wn + j * 16 + m15) * 8];
            #pragma unroll
            for (int i = 0; i < 2; i++)
                #pragma unroll
                for (int j = 0; j < 2; j++)
                    acc[i][j] = __builtin_amdgcn_mfma_f32_16x16x32_bf16(af[i], bf[j], acc[i][j], 0, 0, 0);
        }
    }
    #pragma unroll
    for (int i = 0; i < 2; i++)
        #pragma unroll
        for (int j = 0; j < 2; j++)
            #pragma unroll
            for (int rr = 0; rr < 4; rr++)
                C[(size_t)(m0 + wm + i * 16 + q * 4 + rr) * 1024 + n0 + wn + j * 16 + m15] =
                    acc[i][j][rr];
}

// ---------------- low-rank gate: gk = logsigmoid(x@Wgk1@Wgk2 + b)/16 -> bf16 ----------------
// Wgk1T[j][d] bf16 (coalesced); Wgk2[j][c] f32 (coalesced).
__global__ __launch_bounds__(256) void gk_proj(
    const short* __restrict__ Xb, const short* __restrict__ Wgk1T,
    const float* __restrict__ Wgk2, const float* __restrict__ bgk2,
    short* __restrict__ GK)
{
    const int row = blockIdx.x, tid = threadIdx.x;
    const int d4 = tid * 4;
    sh4 xv = *(const sh4*)(Xb + (size_t)row * 1024 + d4);
    float x0 = bitf(xv[0]), x1 = bitf(xv[1]), x2 = bitf(xv[2]), x3 = bitf(xv[3]);
    float p[16];
    #pragma unroll
    for (int j = 0; j < 16; j++) {
        sh4 w = *(const sh4*)(Wgk1T + j * 1024 + d4);
        p[j] = x0 * bitf(w[0]) + x1 * bitf(w[1]) + x2 * bitf(w[2]) + x3 * bitf(w[3]);
    }
    #pragma unroll
    for (int j = 0; j < 16; j++)
        #pragma unroll
        for (int off = 32; off; off >>= 1) p[j] += __shfl_xor(p[j], off);
    __shared__ float zp[4][16];
    __shared__ float z[16];
    const int lane = tid & 63, w = tid >> 6;
    if (lane == 0) {
        #pragma unroll
        for (int j = 0; j < 16; j++) zp[w][j] = p[j];
    }
    __syncthreads();
    if (tid < 16) z[tid] = zp[0][tid] + zp[1][tid] + zp[2][tid] + zp[3][tid];
    __syncthreads();
    for (int c = tid; c < 1024; c += 256) {
        float acc = bgk2[c];
        #pragma unroll
        for (int j = 0; j < 16; j++)
            acc = fmaf(z[j], Wgk2[j * 1024 + c], acc);
        float ls = fminf(acc, 0.f) - log1pf(expf(-fabsf(acc)));  // logsigmoid
        GK[(size_t)row * 1024 + c] = f2bf(ls * (1.f / 16.f));
    }
}

// ---------------- phase A: chunked scan via MFMA ----------------
// Prologue parallelized over both t-halves; V staged by DMA; O_intra stored bf16.
// S_local stored TRANSPOSED: SS[vch][kch].
__global__ __launch_bounds__(256) void scan_chunk(
    const short* __restrict__ Q, const short* __restrict__ K,
    const short* __restrict__ V, short* GKQT,
    short* __restrict__ O, short* __restrict__ SS, float* __restrict__ DSEG)
{
    const int seg = blockIdx.x;   // 0..15
    const int bh  = blockIdx.y;   // 0..15
    const int b = bh >> 3, h = bh & 7;
    const int tid = threadIdx.x;
    const int wave = tid >> 6, lane = tid & 63;
    const size_t rowbase = (size_t)(b * 512 + seg * SEGLEN) * 1024 + h * 128;

    __shared__ __align__(16) short Qt[32 * QKS];
    __shared__ __align__(16) short Kt[32 * QKS];
    __shared__ __align__(16) short Vs[32 * 128];
    __shared__ __align__(16) short VT[128 * VTS];
    __shared__ __align__(16) short KhT[128 * VTS];
    __shared__ __align__(16) short Am[32 * AMS];
    __shared__ float htot[2][128];

    // DMA stage V: flat f = t*16 + c8 (512 chunks of 8 shorts)
    #pragma unroll
    for (int c = 0; c < 2; c++) {
        const int fb = (wave * 2 + c) * 64;
        const int f = fb + lane;
        const int t = f >> 4, c8 = f & 15;
        gload_lds16(V + rowbase + (size_t)t * 1024 + c8 * 8, &Vs[fb * 8]);
    }

    // prologue: ch = tid&127, th2 = tid>>7 handles 16 t's
    const int ch = tid & 127, th2 = tid >> 7;
    float g[16], kv[16], qv[16];
    #pragma unroll
    for (int tt = 0; tt < 16; tt++) {
        const size_t a = rowbase + (size_t)(th2 * 16 + tt) * 1024 + ch;
        g[tt] = bitf(GKQT[a]); kv[tt] = bitf(K[a]); qv[tt] = bitf(Q[a]);
    }
    float run = 0.f;
    #pragma unroll
    for (int tt = 0; tt < 16; tt++) { run += g[tt]; g[tt] = run; }   // local prefix
    htot[th2][ch] = run;
    __syncthreads();                                  // htot ready
    const float base_ = th2 ? htot[0][ch] : 0.f;
    const float eGend = expf(htot[0][ch] + htot[1][ch]);
    if (th2 == 0) DSEG[(bh * NSEG + seg) * 128 + ch] = eGend;
    #pragma unroll
    for (int tt = 0; tt < 16; tt++) {
        const int t = th2 * 16 + tt;
        const size_t a = rowbase + (size_t)t * 1024 + ch;
        const float Gc = base_ + g[tt];
        const float eg = expf(Gc);
        short qts = f2bf(qv[tt] * eg);
        Qt[t * QKS + ch] = qts;
        GKQT[a] = qts;                       // write Q~ over GK
        float ktv = kv[tt] * expf(-Gc);
        Kt[t * QKS + ch] = f2bf(ktv);
        KhT[ch * VTS + t] = f2bf(ktv * eGend);
    }
    __syncthreads();                                  // Qt/Kt/KhT + V DMA drained
    // V transpose: VT[ch][t]
    {
        const int vch = tid >> 1, t0 = (tid & 1) * 16;
        #pragma unroll
        for (int j = 0; j < 4; j++) {
            sh4 p;
            p[0] = Vs[(t0 + 4 * j + 0) * 128 + vch];
            p[1] = Vs[(t0 + 4 * j + 1) * 128 + vch];
            p[2] = Vs[(t0 + 4 * j + 2) * 128 + vch];
            p[3] = Vs[(t0 + 4 * j + 3) * 128 + vch];
            *(sh4*)&VT[vch * VTS + t0 + 4 * j] = p;
        }
    }
    __syncthreads();

    const int m15 = lane & 15, q = lane >> 4;

    // GEMM1: A = Qt(32x128) @ Kt^T, causal mask, -> Am bf16
    {
        const int mi = wave >> 1, ni = wave & 1;
        f32x4 a1 = (f32x4){0.f, 0.f, 0.f, 0.f};
        #pragma unroll
        for (int kc = 0; kc < 4; kc++) {
            short8 af = *(const short8*)&Qt[(mi * 16 + m15) * QKS + kc * 32 + q * 8];
            short8 bf = *(const short8*)&Kt[(ni * 16 + m15) * QKS + kc * 32 + q * 8];
            a1 = __builtin_amdgcn_mfma_f32_16x16x32_bf16(af, bf, a1, 0, 0, 0);
        }
        #pragma unroll
        for (int rr = 0; rr < 4; rr++) {
            const int t = mi * 16 + q * 4 + rr, s = ni * 16 + m15;
            Am[t * AMS + s] = (t >= s) ? f2bf(a1[rr]) : (short)0;
        }
    }
    __syncthreads();

    // GEMM2: O_intra = Am(32x32) @ V(32x128) -> O global (bf16)
    {
        const int mi = wave >> 1, nb = (wave & 1) * 4;
        short8 af = *(const short8*)&Am[(mi * 16 + m15) * AMS + q * 8];
        #pragma unroll
        for (int jj = 0; jj < 4; jj++) {
            short8 bf = *(const short8*)&VT[((nb + jj) * 16 + m15) * VTS + q * 8];
            f32x4 a2 = (f32x4){0.f, 0.f, 0.f, 0.f};
            a2 = __builtin_amdgcn_mfma_f32_16x16x32_bf16(af, bf, a2, 0, 0, 0);
            #pragma unroll
            for (int rr = 0; rr < 4; rr++)
                O[rowbase + (size_t)(mi * 16 + q * 4 + rr) * 1024 + (nb + jj) * 16 + m15] =
                    f2bf(a2[rr]);
        }
    }

    // GEMM3: S^T[vch][kch] = V^T @ Kh -> SS bf16
    {
        const size_t sbase = (size_t)(bh * NSEG + seg) * 16384;
        #pragma unroll
        for (int m2 = 0; m2 < 2; m2++) {
            const int mrow = wave * 2 + m2;      // vch tile
            short8 af = *(const short8*)&VT[(mrow * 16 + m15) * VTS + q * 8];
            #pragma unroll
            for (int ni = 0; ni < 8; ni++) {     // kch tile
                short8 bf = *(const short8*)&KhT[(ni * 16 + m15) * VTS + q * 8];
                f32x4 a3 = (f32x4){0.f, 0.f, 0.f, 0.f};
                a3 = __builtin_amdgcn_mfma_f32_16x16x32_bf16(af, bf, a3, 0, 0, 0);
                #pragma unroll
                for (int rr = 0; rr < 4; rr++)
                    SS[sbase + (size_t)(mrow * 16 + q * 4 + rr) * 128 + ni * 16 + m15] =
                        f2bf(a3[rr]);
            }
        }
    }
}

// ---------------- phase B: stitch segment states (SS layout [vch][kch], packed dwords) ----------------
__global__ __launch_bounds__(256) void stitch(
    short* __restrict__ SS, const float* __restrict__ DSEG)
{
    const int slice = blockIdx.x;   // 0..15: vch rows [slice*8, slice*8+8)
    const int bh = blockIdx.y, tid = threadIdx.x;
    __shared__ float dloc[NSEG][128];
    for (int i = tid; i < NSEG * 128; i += 256)
        dloc[i >> 7][i & 127] = DSEG[(bh * NSEG + (i >> 7)) * 128 + (i & 127)];
    __syncthreads();
    const int kch0 = (tid * 2) & 127;
    float run[2][2] = {{0.f, 0.f}, {0.f, 0.f}};
    for (int seg = 0; seg < NSEG; seg++) {
        const size_t base = (size_t)(bh * NSEG + seg) * 16384 + slice * 1024;
        const float d0 = dloc[seg][kch0], d1 = dloc[seg][kch0 + 1];
        #pragma unroll
        for (int j = 0; j < 2; j++) {
            unsigned* p = (unsigned*)&SS[base + j * 512 + tid * 2];
            unsigned u = *p;
            float t0 = bitf((short)(u & 0xFFFF));
            float t1 = bitf((short)(u >> 16));
            unsigned w0 = (unsigned short)f2bf(run[j][0]);
            unsigned w1 = (unsigned short)f2bf(run[j][1]);
            *p = w0 | (w1 << 16);                      // S_in for this segment
            run[j][0] = fmaf(run[j][0], d0, t0);
            run[j][1] = fmaf(run[j][1], d1, t1);
        }
    }
}

// ---------------- phase C: MFMA correction + fused gated RMSNorm -> bf16 ----------------
__global__ __launch_bounds__(256) void corr_gnorm(
    const short* __restrict__ QT, const short* __restrict__ SS,
    const short* __restrict__ O, const short* __restrict__ G,
    const float* __restrict__ gnw, short* __restrict__ Obf)
{
    const int seg = blockIdx.x;      // 0..15 (seg 0's S_in is zeros from stitch)
    const int bh = blockIdx.y;
    const int b = bh >> 3, h = bh & 7;
    const int tid = threadIdx.x;
    const int wave = tid >> 6, lane = tid & 63;
    const int m15 = lane & 15, q = lane >> 4;
    const size_t rowbase = (size_t)(b * 512 + seg * SEGLEN) * 1024 + h * 128;
    const size_t sbase = (size_t)(bh * NSEG + seg) * 16384;

    __shared__ __align__(16) short Qs[16 * 32 * 8];    // [k8][t][8]    8 KB
    __shared__ __align__(16) short Ss[16 * 128 * 8];   // [k8][vch][8] 32 KB
    __shared__ __align__(16) short Gs[16 * 32 * 8];    // [vch8][t][8]  8 KB
    __shared__ __align__(16) short Os[16 * 32 * 8];    // [vch8][t][8]  8 KB
    __shared__ float red[4][16];

    // DMA stage Q~ (32 t x 128 kch): flat = k8*32 + t
    #pragma unroll
    for (int c = 0; c < 2; c++) {
        const int fb = (wave * 2 + c) * 64;
        const int f = fb + lane;
        const int k8 = f >> 5, t = f & 31;
        gload_lds16(QT + rowbase + (size_t)t * 1024 + k8 * 8, &Qs[fb * 8]);
    }
    // DMA stage G and O (32 t x 128 vch): flat = vch8*32 + t
    #pragma unroll
    for (int c = 0; c < 2; c++) {
        const int fb = (wave * 2 + c) * 64;
        const int f = fb + lane;
        const int v8 = f >> 5, t = f & 31;
        gload_lds16(G + rowbase + (size_t)t * 1024 + v8 * 8, &Gs[fb * 8]);
        gload_lds16(O + rowbase + (size_t)t * 1024 + v8 * 8, &Os[fb * 8]);
    }
    // DMA stage S^T (128 vch x 128 kch): flat = k8*128 + vch
    #pragma unroll
    for (int c = 0; c < 8; c++) {
        const int fb = wave * 512 + c * 64;
        const int f = fb + lane;
        const int k8 = f >> 7, vch = f & 127;
        gload_lds16(SS + sbase + (size_t)vch * 128 + k8 * 8, &Ss[fb * 8]);
    }
    __syncthreads();

    const int mt = wave >> 1, nh2 = wave & 1;
    f32x4 acc[4];
    #pragma unroll
    for (int nt = 0; nt < 4; nt++) acc[nt] = (f32x4){0.f, 0.f, 0.f, 0.f};
    #pragma unroll
    for (int kb = 0; kb < 4; kb++) {
        short8 af = *(const short8*)&Qs[((kb * 4 + q) * 32 + mt * 16 + m15) * 8];
        #pragma unroll
        for (int nt = 0; nt < 4; nt++) {
            short8 bf = *(const short8*)&Ss[((kb * 4 + q) * 128 + nh2 * 64 + nt * 16 + m15) * 8];
            acc[nt] = __builtin_amdgcn_mfma_f32_16x16x32_bf16(af, bf, acc[nt], 0, 0, 0);
        }
    }

    // o = O_intra + corr; partial row sums of o^2
    float o[4][4];
    float ssq[4] = {0.f, 0.f, 0.f, 0.f};
    #pragma unroll
    for (int nt = 0; nt < 4; nt++) {
        const int vch = nh2 * 64 + nt * 16 + m15;
        #pragma unroll
        for (int rr = 0; rr < 4; rr++) {
            const int t = mt * 16 + q * 4 + rr;
            float ov = bitf(Os[((vch >> 3) * 32 + t) * 8 + (vch & 7)]) + acc[nt][rr];
            o[nt][rr] = ov;
            ssq[rr] = fmaf(ov, ov, ssq[rr]);
        }
    }
    #pragma unroll
    for (int rr = 0; rr < 4; rr++) {
        ssq[rr] += __shfl_xor(ssq[rr], 1);
        ssq[rr] += __shfl_xor(ssq[rr], 2);
        ssq[rr] += __shfl_xor(ssq[rr], 4);
        ssq[rr] += __shfl_xor(ssq[rr], 8);
    }
    if (m15 == 0) {
        #pragma unroll
        for (int rr = 0; rr < 4; rr++) red[wave][q * 4 + rr] = ssq[rr];
    }
    __syncthreads();
    float rsq[4];
    #pragma unroll
    for (int rr = 0; rr < 4; rr++) {
        float ms = (red[wave][q * 4 + rr] + red[wave ^ 1][q * 4 + rr]) * (1.f / 128.f);
        rsq[rr] = rsqrtf(ms + 1e-5f);
    }
    #pragma unroll
    for (int nt = 0; nt < 4; nt++) {
        const int vch = nh2 * 64 + nt * 16 + m15;
        const float gw = gnw[vch];
        #pragma unroll
        for (int rr = 0; rr < 4; rr++) {
            const int t = mt * 16 + q * 4 + rr;
            float g = bitf(Gs[((vch >> 3) * 32 + t) * 8 + (vch & 7)]);
            float sg = g / (1.f + expf(-g));
            Obf[rowbase + (size_t)t * 1024 + vch] = f2bf(o[nt][rr] * rsq[rr] * gw * sg);
        }
    }
}

extern "C" void kernel_launch(void* const* d_in, const int* in_sizes, int n_in,
                              void* d_out, int out_size, void* d_ws, size_t ws_size,
                              hipStream_t stream)
{
    const float* X    = (const float*)d_in[0];
    const float* Wq   = (const float*)d_in[1];
    const float* Wk   = (const float*)d_in[2];
    const float* Wv   = (const float*)d_in[3];
    const float* Wg   = (const float*)d_in[4];
    const float* Wgk1 = (const float*)d_in[5];
    const float* Wgk2 = (const float*)d_in[6];
    const float* bgk2 = (const float*)d_in[7];
    const float* gnw  = (const float*)d_in[8];
    const float* Wo   = (const float*)d_in[9];
    float* OUT = (float*)d_out;   // reference output is float32

    // workspace layout (shorts unless noted, ~32 MiB):
    short* QKVG  = (short*)d_ws;               // 4 x 1M bf16 (Q,K,V,G)     [8 MiB]
    short* GK    = QKVG + (4u << 20);          // 1M bf16: GK -> Q~         [2 MiB]
    short* Ob    = GK + (1u << 20);            // 1M bf16 O_intra           [2 MiB]
    short* SS    = Ob + (1u << 20);            // 16bh x 16seg x [vch][kch] [8 MiB]
    float* DS    = (float*)(SS + (4u << 20));  // 32K f32                   [128 KiB]
    short* WT    = (short*)(DS + 32768);       // 5 x 1M bf16 (W^T)         [10 MiB]
    short* Xb    = WT + (5u << 20);            // 1M bf16 (X cast)          [2 MiB]
    short* Wgk1T = Xb + (1u << 20);            // 16K bf16 (Wgk1^T)         [32 KiB]
    short* Obf   = QKVG;                       // alias Q (dead after scan_chunk)

    cast_all<<<dim3(32, 32, 7), 256, 0, stream>>>(Wq, Wk, Wv, Wg, Wo, X, Wgk1, WT, Xb, Wgk1T);
    proj_gemm<<<dim3(8, 16, 4), 256, 0, stream>>>(Xb, WT, QKVG);
    gk_proj<<<dim3(BT), 256, 0, stream>>>(Xb, Wgk1T, Wgk2, bgk2, GK);
    scan_chunk<<<dim3(NSEG, NBH), 256, 0, stream>>>(
        QKVG, QKVG + (1u << 20), QKVG + (2u << 20), GK, Ob, SS, DS);
    stitch<<<dim3(16, NBH), 256, 0, stream>>>(SS, DS);
    corr_gnorm<<<dim3(NSEG, NBH), 256, 0, stream>>>(
        GK, SS, Ob, QKVG + (3u << 20), gnw, Obf);
    wo_gemm<<<dim3(16, 16), 256, 0, stream>>>(Obf, WT + (4u << 20), OUT);
}